// Round 9
// baseline (421.223 us; speedup 1.0000x reference)
//
#include <hip/hip_runtime.h>
#include <hip/hip_bf16.h>

// CAPERNN_ContRoles_HPN — round 13:
//  (a) gemm_gru 8-wave (512 thr): wave = 16x32 sub-tile of all 4 gates -> 32 waves/CU
//      (4 blocks x 40KB LDS = 160KB, 4x512 = 2048 threads: exact CU fill). GRU fusion kept.
//  (b) QKS gemm (K=32) fused into glue_attn: qk computed from own-bf16 x WQKSO (L2-hot)
//      + qksb; QKSb buffer + OWNb cvt + one launch removed.
//  Generic gemms reverted to round-11 measured-best (BK=32, 16KB dbuf).
// M = BN = 16384, H=256, NH=4, HD=64, NA=15, NE=16, RD=8, NMOVE=6.

#define MROWS 16384

typedef __attribute__((ext_vector_type(8))) short short8;
typedef __attribute__((ext_vector_type(4))) float float4v;
typedef __attribute__((ext_vector_type(4))) unsigned short ushort4v;
typedef __attribute__((ext_vector_type(2))) unsigned short ushort2v;

__device__ __forceinline__ unsigned short f2b(float f) {
    __hip_bfloat16 h = __float2bfloat16(f);
    return *reinterpret_cast<unsigned short*>(&h);
}
__device__ __forceinline__ float b2f(unsigned short u) {
    __hip_bfloat16 h;
    *reinterpret_cast<unsigned short*>(&h) = u;
    return __bfloat162float(h);
}
__device__ __forceinline__ void gll16(const unsigned short* g, unsigned short* l) {
    __builtin_amdgcn_global_load_lds((const __attribute__((address_space(1))) void*)g,
                                     (__attribute__((address_space(3))) void*)l, 16, 0, 0);
}

// ---------------- prep: hidden->XG[264:520], zero zbuf ----------------
__global__ void cvt_misc(const float* __restrict__ hidden,
                         unsigned short* __restrict__ XG,
                         unsigned short* __restrict__ zbuf) {
    int idx = blockIdx.x * 256 + threadIdx.x;
    const int nh = MROWS * 64;        // hidden: 4 elems/thread
    if (idx < nh) {
        int row = idx >> 6, c4 = (idx & 63) * 4;
        float4 v = *(const float4*)(hidden + (size_t)row * 256 + c4);
        ushort4v d = { f2b(v.x), f2b(v.y), f2b(v.z), f2b(v.w) };
        *(ushort4v*)(XG + (size_t)row * 520 + 264 + c4) = d;
    } else if (idx < nh + 16) {
        int j = idx - nh;
        ((uint4*)zbuf)[j] = make_uint4(0u, 0u, 0u, 0u);   // 256 B zeros
    }
}

// ---------------- tiled compose: 32x32 output tiles, LDS-staged ----------------
// type 0: matmul->bf16, 1: matmul->fp32, 2: cvt copy->bf16, 3: zero bf16
struct TOp {
    int type;
    const float* A; int sAi, sAk;
    const float* B; int sBj, sBk;
    void* O; int sOi;
    int I, J, K;
    int nb; int aB, bB, oB;
};
struct TOpSet { int n; int tiles[26]; TOp ops[26]; };

__global__ __launch_bounds__(256)
void compose_tiled(TOpSet S) {
    int t = blockIdx.x;
    int op = 0;
    while (op < S.n && t >= S.tiles[op]) { t -= S.tiles[op]; op++; }
    if (op >= S.n) return;
    TOp o = S.ops[op];
    int ti = (o.I + 31) >> 5, tj = (o.J + 31) >> 5;
    int per = ti * tj;
    int b = t / per;
    int rem = t - b * per;
    int i0 = (rem / tj) * 32, j0 = (rem % tj) * 32;
    int tid = threadIdx.x;
    if (o.type >= 2) {
        for (int e = tid; e < 1024; e += 256) {
            int r = e >> 5, c = e & 31;
            int i = i0 + r, j = j0 + c;
            if (i < o.I && j < o.J) {
                unsigned short v = 0;
                if (o.type == 2) v = f2b(o.A[(long)b * o.aB + (long)i * o.sAi + (long)j * o.sAk]);
                ((unsigned short*)o.O)[(long)b * o.oB + (long)i * o.sOi + j] = v;
            }
        }
        return;
    }
    __shared__ float As[32][33];
    __shared__ float Bs[32][33];
    int tx = tid & 15, ty = tid >> 4;
    float a00 = 0.f, a01 = 0.f, a10 = 0.f, a11 = 0.f;
    const float* Ab = o.A + (long)b * o.aB;
    const float* Bb = o.B + (long)b * o.bB;
    for (int k0 = 0; k0 < o.K; k0 += 32) {
        for (int e = tid; e < 1024; e += 256) {
            int r = e >> 5, c = e & 31;
            As[r][c] = (i0 + r < o.I && k0 + c < o.K)
                       ? Ab[(long)(i0 + r) * o.sAi + (long)(k0 + c) * o.sAk] : 0.f;
            Bs[r][c] = (k0 + r < o.K && j0 + c < o.J)
                       ? Bb[(long)(j0 + c) * o.sBj + (long)(k0 + r) * o.sBk] : 0.f;
        }
        __syncthreads();
#pragma unroll
        for (int k = 0; k < 32; k++) {
            float x0 = As[ty * 2][k], x1 = As[ty * 2 + 1][k];
            float y0 = Bs[k][tx * 2], y1 = Bs[k][tx * 2 + 1];
            a00 += x0 * y0; a01 += x0 * y1; a10 += x1 * y0; a11 += x1 * y1;
        }
        __syncthreads();
    }
    int i = i0 + ty * 2, j = j0 + tx * 2;
    float vals[2][2] = {{a00, a01}, {a10, a11}};
#pragma unroll
    for (int di = 0; di < 2; di++)
#pragma unroll
        for (int dj = 0; dj < 2; dj++) {
            int ii = i + di, jj = j + dj;
            if (ii < o.I && jj < o.J) {
                long oidx = (long)b * o.oB + (long)ii * o.sOi + jj;
                if (o.type == 0) ((unsigned short*)o.O)[oidx] = f2b(vals[di][dj]);
                else ((float*)o.O)[oidx] = vals[di][dj];
            }
        }
}

// ---------------- matvec ops: one wave per output ----------------
struct MOp { const float* A; int sAi; const float* x; const float* b1; const float* b2; float* out; int I, K; };
struct MOpSet { int n; int waves[10]; MOp ops[10]; };

__global__ void mv_ops(MOpSet S) {
    int wid = blockIdx.x * 4 + (threadIdx.x >> 6);
    int lane = threadIdx.x & 63;
    int op = 0;
    while (op < S.n && wid >= S.waves[op]) { wid -= S.waves[op]; op++; }
    if (op >= S.n) return;
    MOp o = S.ops[op];
    float s = 0.f;
    for (int k = lane; k < o.K; k += 64) s += o.A[(long)wid * o.sAi + k] * o.x[k];
    for (int off = 32; off; off >>= 1) s += __shfl_xor(s, off, 64);
    if (lane == 0) {
        if (o.b1) s += o.b1[wid];
        if (o.b2) s += o.b2[wid];
        o.out[wid] = s;
    }
}

// ---------------- bf16 MFMA GEMM: C[MxN] = A[MxK] @ W[NxK]^T (+bias)(+gelu) ----------------
// Round-11 config: 64x64 tile, 4 waves 2x2, BK=32, 2-buf LDS (16KB), round-7 step scheme.
template<int BM, int BN>
__global__ __launch_bounds__(256, 4)
void gemm_bf16(const unsigned short* __restrict__ A, int lda,
               const unsigned short* __restrict__ W,
               const float* __restrict__ bias,
               unsigned short* __restrict__ C, int ldc,
               int N, int K, int act,
               const unsigned short* __restrict__ zbuf) {
    constexpr int MI = BM / 32, NJ = BN / 32;
    __shared__ __align__(16) unsigned short As[2][BM * 32];
    __shared__ __align__(16) unsigned short Bs[2][BN * 32];
    int tid = threadIdx.x;
    int m0 = blockIdx.x * BM, n0 = blockIdx.y * BN;
    int wave = tid >> 6, lane = tid & 63;
    int wm = (wave & 1) * (BM / 2), wn = (wave >> 1) * (BN / 2);
    int l16 = lane & 15, quad = lane >> 4;

    float4v acc[MI][NJ];
#pragma unroll
    for (int i = 0; i < MI; i++)
#pragma unroll
        for (int j = 0; j < NJ; j++) acc[i][j] = (float4v){0.f, 0.f, 0.f, 0.f};

    int swz = ((l16 >> 1) & 3) * 8;
    int nt = (K + 31) >> 5;

    auto stage = [&](int buf, int k0) {
#pragma unroll
        for (int s0 = 0; s0 < BM * 4; s0 += 256) {
            int s = s0 + tid;
            int row = s >> 2;
            int cg = (s & 3) ^ ((row >> 1) & 3);
            int ka = k0 + cg * 8;
            gll16((ka < K) ? A + (size_t)(m0 + row) * lda + ka : zbuf, &As[buf][s * 8]);
        }
#pragma unroll
        for (int s0 = 0; s0 < BN * 4; s0 += 256) {
            int s = s0 + tid;
            int row = s >> 2;
            int cg = (s & 3) ^ ((row >> 1) & 3);
            int ka = k0 + cg * 8;
            gll16((ka < K && n0 + row < N) ? W + (size_t)(n0 + row) * K + ka : zbuf,
                  &Bs[buf][s * 8]);
        }
    };
    auto compute = [&](int buf) {
        short8 a[MI], b[NJ];
#pragma unroll
        for (int i = 0; i < MI; i++)
            a[i] = *(const short8*)(&As[buf][(wm + i * 16 + l16) * 32 + ((quad * 8) ^ swz)]);
#pragma unroll
        for (int j = 0; j < NJ; j++)
            b[j] = *(const short8*)(&Bs[buf][(wn + j * 16 + l16) * 32 + ((quad * 8) ^ swz)]);
#pragma unroll
        for (int i = 0; i < MI; i++)
#pragma unroll
            for (int j = 0; j < NJ; j++)
                acc[i][j] = __builtin_amdgcn_mfma_f32_16x16x32_bf16(a[i], b[j], acc[i][j], 0, 0, 0);
    };

    stage(0, 0);
    asm volatile("s_waitcnt vmcnt(0)" ::: "memory");
    __builtin_amdgcn_s_barrier();
    for (int t = 0; t < nt - 1; t++) {
        stage((t + 1) & 1, (t + 1) << 5);   // next tile in flight during compute
        compute(t & 1);
        asm volatile("s_waitcnt vmcnt(0)" ::: "memory");
        __builtin_amdgcn_s_barrier();
    }
    compute((nt - 1) & 1);

#pragma unroll
    for (int i = 0; i < MI; i++) {
#pragma unroll
        for (int j = 0; j < NJ; j++) {
#pragma unroll
            for (int rr = 0; rr < 4; rr++) {
                int rowm = m0 + wm + i * 16 + quad * 4 + rr;
                int coln = wn + j * 16 + l16;
                if (n0 + coln >= N) continue;
                float v = acc[i][j][rr];
                if (bias) v += bias[n0 + coln];
                if (act == 1) v = 0.5f * v * (1.f + erff(v * 0.70710678f));
                C[(size_t)rowm * ldc + n0 + coln] = f2b(v);
            }
        }
    }
}

// ---------------- 4-gate fused GRU GEMM + nonlinearity, 8 waves (512 threads) ----------------
// Wave w: rows [wm=(w&3)*16, +16), cols [wn=(w>>2)*32, +32) of ALL 4 gates -> acc[4][2].
// 4 blocks/CU x 8 waves = 32 waves/CU (LDS 4x40KB=160KB, threads 4x512=2048: exact fill).
__global__ __launch_bounds__(512, 4)
void gemm_gru(const unsigned short* __restrict__ A, int lda,        // XG, lda=520
              const unsigned short* __restrict__ W,                 // WGRU [1024][520]
              const float* __restrict__ gbias,                      // [1024]
              const float* __restrict__ hp,                         // h_prev f32 [M][256]
              float* __restrict__ hout, unsigned short* __restrict__ XQ,
              int K, const unsigned short* __restrict__ zbuf) {
    __shared__ __align__(16) unsigned short As[2][64 * 32];
    __shared__ __align__(16) unsigned short Ws[2][4 * 64 * 32];
    int tid = threadIdx.x;
    int m0 = blockIdx.x * 64, n0 = blockIdx.y * 64;
    int wave = tid >> 6, lane = tid & 63;
    int wm = (wave & 3) * 16, wn = (wave >> 2) * 32;
    int l16 = lane & 15, quad = lane >> 4;

    float4v acc[4][2];
#pragma unroll
    for (int g = 0; g < 4; g++)
#pragma unroll
        for (int j = 0; j < 2; j++) acc[g][j] = (float4v){0.f, 0.f, 0.f, 0.f};

    int swz = ((l16 >> 1) & 3) * 8;
    int nt = (K + 31) >> 5;

    // staging: A slots 0..255 (threads < 256), W slots 0..1023 (2 per thread)
    const unsigned short* Aptr = A;   // only valid for tid<256
    int aKoff = 0;
    if (tid < 256) {
        int row = tid >> 2;
        int cg = (tid & 3) ^ ((row >> 1) & 3);
        Aptr = A + (size_t)(m0 + row) * lda + cg * 8;
        aKoff = cg * 8;
    }
    const unsigned short* Wptr[2];
    int wKoff[2];
    int wSlot0 = tid, wSlot1 = tid + 512;
    {
        int s = wSlot0;
        int g = s >> 8, s8 = s & 255;
        int row = s8 >> 2;
        int cg = (s8 & 3) ^ ((row >> 1) & 3);
        Wptr[0] = W + (size_t)(g * 256 + n0 + row) * K + cg * 8;
        wKoff[0] = cg * 8;
        s = wSlot1;
        g = s >> 8; s8 = s & 255;
        row = s8 >> 2;
        cg = (s8 & 3) ^ ((row >> 1) & 3);
        Wptr[1] = W + (size_t)(g * 256 + n0 + row) * K + cg * 8;
        wKoff[1] = cg * 8;
    }

    auto stage = [&](int buf, int k0) {
        if (tid < 256)
            gll16((k0 + aKoff < K) ? Aptr + k0 : zbuf, &As[buf][tid * 8]);
        gll16((k0 + wKoff[0] < K) ? Wptr[0] + k0 : zbuf, &Ws[buf][wSlot0 * 8]);
        gll16((k0 + wKoff[1] < K) ? Wptr[1] + k0 : zbuf, &Ws[buf][wSlot1 * 8]);
    };
    auto compute = [&](int buf) {
        short8 a = *(const short8*)(&As[buf][(wm + l16) * 32 + ((quad * 8) ^ swz)]);
        short8 b[4][2];
#pragma unroll
        for (int g = 0; g < 4; g++)
#pragma unroll
            for (int j = 0; j < 2; j++)
                b[g][j] = *(const short8*)(&Ws[buf][g * 2048 + (wn + j * 16 + l16) * 32 + ((quad * 8) ^ swz)]);
#pragma unroll
        for (int g = 0; g < 4; g++)
#pragma unroll
            for (int j = 0; j < 2; j++)
                acc[g][j] = __builtin_amdgcn_mfma_f32_16x16x32_bf16(a, b[g][j], acc[g][j], 0, 0, 0);
    };

    stage(0, 0);
    asm volatile("s_waitcnt vmcnt(0)" ::: "memory");
    __builtin_amdgcn_s_barrier();
    for (int t = 0; t < nt - 1; t++) {
        stage((t + 1) & 1, (t + 1) << 5);
        compute(t & 1);
        asm volatile("s_waitcnt vmcnt(0)" ::: "memory");
        __builtin_amdgcn_s_barrier();
    }
    compute((nt - 1) & 1);

#pragma unroll
    for (int j = 0; j < 2; j++) {
#pragma unroll
        for (int rr = 0; rr < 4; rr++) {
            int rowm = m0 + wm + quad * 4 + rr;
            int coln = n0 + wn + j * 16 + l16;            // h-column 0..255
            float r_ = acc[0][j][rr] + gbias[coln];
            float z_ = acc[1][j][rr] + gbias[256 + coln];
            float in_ = acc[2][j][rr] + gbias[512 + coln];
            float hn_ = acc[3][j][rr] + gbias[768 + coln];
            float rg = 1.f / (1.f + __expf(-r_));
            float zg = 1.f / (1.f + __expf(-z_));
            float ng = tanhf(in_ + rg * hn_);
            float h = (1.f - zg) * ng + zg * hp[(size_t)rowm * 256 + coln];
            hout[(size_t)rowm * 256 + coln] = h;
            XQ[(size_t)rowm * 264 + coln] = f2b(h);
        }
    }
}

// ---------------- combined LN: FPC[:,0:256]->XG(ld520), FPC[:,256:384]->T2 ----------------
__global__ __launch_bounds__(256)
void ln_fp(const unsigned short* __restrict__ FPC,
           const float* __restrict__ g1, const float* __restrict__ be1,
           const float* __restrict__ g2, const float* __restrict__ be2,
           unsigned short* __restrict__ XG, unsigned short* __restrict__ T2) {
    int tid = threadIdx.x;
    size_t row = (size_t)blockIdx.x * 4 + (tid >> 6);
    int l = tid & 63;
    const unsigned short* src = FPC + row * 384;
    ushort4v vf = *(const ushort4v*)(src + l * 4);
    ushort2v vp = *(const ushort2v*)(src + 256 + l * 2);
    float f0 = b2f(vf[0]), f1 = b2f(vf[1]), f2v = b2f(vf[2]), f3 = b2f(vf[3]);
    float p0 = b2f(vp[0]), p1 = b2f(vp[1]);
    float s = f0 + f1 + f2v + f3;
    float q = f0 * f0 + f1 * f1 + f2v * f2v + f3 * f3;
    float s2 = p0 + p1, q2 = p0 * p0 + p1 * p1;
    for (int o = 32; o; o >>= 1) {
        s += __shfl_xor(s, o, 64); q += __shfl_xor(q, o, 64);
        s2 += __shfl_xor(s2, o, 64); q2 += __shfl_xor(q2, o, 64);
    }
    float mean = s * (1.f / 256.f);
    float rstd = rsqrtf(q * (1.f / 256.f) - mean * mean + 1e-5f);
    float4 g = *(const float4*)(g1 + l * 4);
    float4 be = *(const float4*)(be1 + l * 4);
    ushort4v o4;
    o4[0] = f2b((f0 - mean) * rstd * g.x + be.x);
    o4[1] = f2b((f1 - mean) * rstd * g.y + be.y);
    o4[2] = f2b((f2v - mean) * rstd * g.z + be.z);
    o4[3] = f2b((f3 - mean) * rstd * g.w + be.w);
    *(ushort4v*)(XG + row * 520 + l * 4) = o4;
    float mean2 = s2 * (1.f / 128.f);
    float rstd2 = rsqrtf(q2 * (1.f / 128.f) - mean2 * mean2 + 1e-5f);
    float2 gg = *(const float2*)(g2 + l * 2);
    float2 bb = *(const float2*)(be2 + l * 2);
    ushort2v o2;
    o2[0] = f2b((p0 - mean2) * rstd2 * gg.x + bb.x);
    o2[1] = f2b((p1 - mean2) * rstd2 * gg.y + bb.y);
    *(ushort2v*)(T2 + row * 128 + l * 2) = o2;
}

// ---------------- attention glue + fused QKS (4 rows/block) ----------------
// qk[r][c] = sum_k bf16(own[r][k]) * WQKSO[c][k] + qksb[c]  (replaces QKS gemm + QKSb)
__global__ __launch_bounds__(256)
void glue_attn(const float* __restrict__ allyf, const float* __restrict__ enemyf,
               const float* __restrict__ ownf, const unsigned short* __restrict__ WQKSO,
               const float* __restrict__ qksb, unsigned short* __restrict__ X) {
    __shared__ __align__(16) float af[4][540];    // 15 x 36
    __shared__ __align__(16) float ef[4][576];    // 16 x 36
    __shared__ __align__(16) float qk[4][288];    // 8 head-chunks x 36
    __shared__ float ow[4][32];                   // own rows (bf16-rounded)
    __shared__ float attnA[4][64];
    __shared__ float attnE[4][64];
    __shared__ float mskA[4][16];
    __shared__ float mskE[4][16];
    int tid = threadIdx.x;
    size_t rb = (size_t)blockIdx.x * 4;

    for (int idx = tid; idx < 480; idx += 256) {          // ally: 120 float4 / row
        int r = idx / 120, ch = idx - r * 120;
        float4 v = *(const float4*)(allyf + ((rb + r) * 480 + ch * 4));
        *(float4*)&af[r][(ch >> 3) * 36 + (ch & 7) * 4] = v;
    }
    for (int idx = tid; idx < 512; idx += 256) {          // enemy: 128 float4 / row
        int r = idx >> 7, ch = idx & 127;
        float4 v = *(const float4*)(enemyf + ((rb + r) * 512 + ch * 4));
        *(float4*)&ef[r][(ch >> 3) * 36 + (ch & 7) * 4] = v;
    }
    if (tid >= 128 && tid < 256) {                         // own copy + ow (bf16-rounded)
        int r = (tid - 128) >> 5, c = (tid - 128) & 31;
        unsigned short ob = f2b(ownf[(rb + r) * 32 + c]);
        X[(rb + r) * 360 + c] = ob;
        ow[r][c] = b2f(ob);
    }
    if (tid < 24) {
        int r = tid / 6, c = 98 + tid % 6;
        X[(rb + r) * 360 + c] = 0;
    }
    __syncthreads();

    // masks: 2 lanes per (row, entity), float4 scans + pair shfl
    if (tid < 248) {
        int pair = tid >> 1, half = tid & 1;
        int r = pair / 31, e = pair - r * 31;
        const float* base = (e < 15) ? &af[r][e * 36] : &ef[r][(e - 15) * 36];
        const float4* b4 = (const float4*)base + half * 4;
        bool nz = false;
#pragma unroll
        for (int k = 0; k < 4; k++) {
            float4 v = b4[k];
            nz |= (v.x != 0.f) || (v.y != 0.f) || (v.z != 0.f) || (v.w != 0.f);
        }
        int other = __shfl_xor((int)nz, 1, 64);
        float mv = (nz || other != 0) ? 1.f : 0.f;
        if (half == 0) {
            if (e < 15) mskA[r][e] = mv; else mskE[r][e - 15] = mv;
        }
    } else if (tid < 252) {
        mskA[tid - 248][15] = 0.f;
    }
    // fused QKS: each thread computes 4 consecutive cols of its row's qk
    {
        int r = tid >> 6, cb = (tid & 63) * 4;
        const float* owr = ow[r];
#pragma unroll
        for (int cc = 0; cc < 4; cc++) {
            int c = cb + cc;
            const unsigned short* wr = WQKSO + c * 32;
            float s = qksb[c];
#pragma unroll
            for (int k = 0; k < 32; k += 8) {
                short8 wv = *(const short8*)(wr + k);
#pragma unroll
                for (int j = 0; j < 8; j++)
                    s += owr[k + j] * b2f((unsigned short)wv[j]);
            }
            qk[r][(c >> 5) * 36 + (c & 31)] = s;
        }
    }
    __syncthreads();

    int r = tid >> 6, lane = tid & 63;
    int h = lane >> 4, m = lane & 15;
    // ally softmax (15 entities)
    {
        float sc = -3.0e38f;
        if (m < 15) {
            const float4* qa = (const float4*)&qk[r][h * 36];
            const float4* aa = (const float4*)&af[r][m * 36];
            float s = 0.f;
#pragma unroll
            for (int k = 0; k < 8; k++) {
                float4 q = qa[k], a = aa[k];
                s += q.x * a.x + q.y * a.y + q.z * a.z + q.w * a.w;
            }
            sc = (mskA[r][m] > 0.f) ? s * 0.125f : -1e9f;
        }
        float mx = sc;
        for (int o = 8; o; o >>= 1) mx = fmaxf(mx, __shfl_xor(mx, o, 64));
        float e = (m < 15) ? __expf(sc - mx) : 0.f;
        float sm = e;
        for (int o = 8; o; o >>= 1) sm += __shfl_xor(sm, o, 64);
        attnA[r][h * 16 + m] = e / sm;
    }
    // enemy softmax (16 entities)
    {
        const float4* qa = (const float4*)&qk[r][(4 + h) * 36];
        const float4* aa = (const float4*)&ef[r][m * 36];
        float s = 0.f;
#pragma unroll
        for (int k = 0; k < 8; k++) {
            float4 q = qa[k], a = aa[k];
            s += q.x * a.x + q.y * a.y + q.z * a.z + q.w * a.w;
        }
        float sc = (mskE[r][m] > 0.f) ? s * 0.125f : -1e9f;
        float mx = sc;
        for (int o = 8; o; o >>= 1) mx = fmaxf(mx, __shfl_xor(mx, o, 64));
        float e = __expf(sc - mx);
        float sm = e;
        for (int o = 8; o; o >>= 1) sm += __shfl_xor(sm, o, 64);
        attnE[r][h * 16 + m] = e / sm;
    }
    __syncthreads();
    size_t row = rb + r;
#pragma unroll
    for (int it = 0; it < 2; it++) {
        int idx = lane + it * 64;
        int hh = idx >> 5, c = idx & 31;
        float sA = 0.f;
        for (int mm = 0; mm < 15; mm++) sA += attnA[r][hh * 16 + mm] * af[r][mm * 36 + c];
        X[row * 360 + 104 + idx] = f2b(sA);
        float sE = 0.f;
        for (int mm = 0; mm < 16; mm++) sE += attnE[r][hh * 16 + mm] * ef[r][mm * 36 + c];
        X[row * 360 + 232 + idx] = f2b(sE);
    }
    if (lane < 32) {
        float cnt = 0.f;
        for (int mm = 0; mm < 15; mm++) cnt += mskA[r][mm];
        float s = 0.f;
        for (int mm = 0; mm < 15; mm++) s += af[r][mm * 36 + lane];
        X[row * 360 + 32 + lane] = f2b(s / fmaxf(cnt, 1e-8f));
        if (lane == 0) X[row * 360 + 96] = f2b(cnt > 0.f ? 1.f : 0.f);
    } else {
        int c = lane - 32;
        float cnt = 0.f;
        for (int mm = 0; mm < 16; mm++) cnt += mskE[r][mm];
        float s = 0.f;
        for (int mm = 0; mm < 16; mm++) s += ef[r][mm * 36 + c];
        X[row * 360 + 64 + c] = f2b(s / fmaxf(cnt, 1e-8f));
        if (c == 0) X[row * 360 + 97] = f2b(cnt > 0.f ? 1.f : 0.f);
    }
}

// ---------------- fused LN(128) + role head -> XG cols 256..264 (+ XQ copy) ----------------
__global__ __launch_bounds__(256)
void ln_role(const unsigned short* __restrict__ T3, const float* __restrict__ g1,
             const float* __restrict__ be1, const float* __restrict__ W2,
             const float* __restrict__ b2, const float* __restrict__ rg,
             const float* __restrict__ rb, unsigned short* __restrict__ XG,
             unsigned short* __restrict__ XQ) {
    __shared__ float t3[32][132];
    __shared__ float gl[128], bl[128];
    int tid = threadIdx.x;
    size_t base = (size_t)blockIdx.x * 4096;
    for (int idx = tid; idx < 4096; idx += 256)
        t3[idx >> 7][idx & 127] = b2f(T3[base + idx]);
    if (tid < 128) { gl[tid] = g1[tid]; bl[tid] = be1[tid]; }
    __syncthreads();
    int r = tid >> 3, t = tid & 7;
    float s = 0.f, q = 0.f;
    for (int c = 0; c < 16; c++) { float v = t3[r][t * 16 + c]; s += v; q += v * v; }
    for (int o = 4; o; o >>= 1) { s += __shfl_xor(s, o, 8); q += __shfl_xor(q, o, 8); }
    float mean = s * (1.f / 128.f);
    float var = q * (1.f / 128.f) - mean * mean;
    float rstd = rsqrtf(var + 1e-5f);
    float acc = b2[t];
    const float* w = W2 + t * 128;
    for (int d = 0; d < 128; d++)
        acc += w[d] * ((t3[r][d] - mean) * rstd * gl[d] + bl[d]);
    float v = tanhf(acc);
    float mn = v;
    for (int o = 4; o; o >>= 1) mn += __shfl_xor(mn, o, 8);
    mn *= 0.125f;
    float dv = v - mn, qq = dv * dv;
    for (int o = 4; o; o >>= 1) qq += __shfl_xor(qq, o, 8);
    qq *= 0.125f;
    size_t row = (size_t)blockIdx.x * 32 + r;
    unsigned short ov = f2b(dv * rsqrtf(qq + 1e-5f) * rg[t] + rb[t]);
    XG[row * 520 + 256 + t] = ov;
    XQ[row * 264 + 256 + t] = ov;
}

// ---------------- final heads ----------------
__global__ __launch_bounds__(256)
void glue_final(const unsigned short* __restrict__ QWS, const float* __restrict__ efeats,
                const float* __restrict__ qnb, float* __restrict__ Q) {
    __shared__ __align__(16) float ef[8][576];   // 16 x 36
    __shared__ __align__(16) float qw[8][40];
    int tid = threadIdx.x;
    size_t rb = (size_t)blockIdx.x * 8;
    for (int idx = tid; idx < 1024; idx += 256) {        // 128 float4 / row
        int r = idx >> 7, ch = idx & 127;
        float4 v = *(const float4*)(efeats + (rb + r) * 512 + ch * 4);
        *(float4*)&ef[r][(ch >> 3) * 36 + (ch & 7) * 4] = v;
    }
    for (int idx = tid; idx < 320; idx += 256) {
        int r = idx / 40, c = idx % 40;
        qw[r][c] = b2f(QWS[(rb + r) * 40 + c]);
    }
    __syncthreads();
    int r = tid >> 5, t = tid & 31;
    size_t row = rb + r;
    float lg = 0.f, mk = 0.f;
    if (t < 16) {
        const float4* fr = (const float4*)&ef[r][t * 36];
        const float4* qv = (const float4*)&qw[r][0];
        bool nz = false;
        float s = 0.f;
#pragma unroll
        for (int k = 0; k < 8; k++) {
            float4 a = fr[k], b = qv[k];
            nz |= (a.x != 0.f) || (a.y != 0.f) || (a.z != 0.f) || (a.w != 0.f);
            s += a.x * b.x + a.y * b.y + a.z * b.z + a.w * b.w;
        }
        mk = nz ? 1.f : 0.f;
        lg = (s + qw[r][32]) * 0.0625f;
    }
    float sv = mk * lg, cv = mk;
    for (int o = 8; o; o >>= 1) { sv += __shfl_xor(sv, o, 64); cv += __shfl_xor(cv, o, 64); }
    float mean = sv / fmaxf(cv, 1.f);
    if (t < 16) Q[row * 22 + 6 + t] = (mk > 0.f ? lg : -1e9f) - mean;
    if (t < 6) Q[row * 22 + t] = qw[r][33 + t] + qnb[t];
}

// ---------------- host orchestration ----------------
extern "C" void kernel_launch(void* const* d_in, const int* in_sizes, int n_in,
                              void* d_out, int out_size, void* d_ws, size_t ws_size,
                              hipStream_t stream) {
    const float* own_feats = (const float*)d_in[1];
    const float* ally_feats = (const float*)d_in[2];
    const float* enemy_feats = (const float*)d_in[3];
    const float* hidden = (const float*)d_in[4];
    const float* own_W = (const float*)d_in[5];   const float* own_b = (const float*)d_in[6];
    const float* ally_W = (const float*)d_in[7];  const float* ally_b = (const float*)d_in[8];
    const float* en_W = (const float*)d_in[9];    const float* en_b = (const float*)d_in[10];
    const float* aA_Wq = (const float*)d_in[11];  const float* aA_Wk = (const float*)d_in[12];
    const float* aA_Wv = (const float*)d_in[13];  const float* aA_Wo = (const float*)d_in[14];
    const float* aE_Wq = (const float*)d_in[15];  const float* aE_Wk = (const float*)d_in[16];
    const float* aE_Wv = (const float*)d_in[17];  const float* aE_Wo = (const float*)d_in[18];
    const float* fuse_W1 = (const float*)d_in[19]; const float* fuse_b1 = (const float*)d_in[20];
    const float* fuse_g1 = (const float*)d_in[21]; const float* fuse_be1 = (const float*)d_in[22];
    const float* fuse_W2 = (const float*)d_in[23]; const float* fuse_b2 = (const float*)d_in[24];
    const float* pool_W1 = (const float*)d_in[25]; const float* pool_b1 = (const float*)d_in[26];
    const float* pool_g1 = (const float*)d_in[27]; const float* pool_be1 = (const float*)d_in[28];
    const float* pool_W2 = (const float*)d_in[29]; const float* pool_b2 = (const float*)d_in[30];
    const float* role_W1 = (const float*)d_in[31]; const float* role_b1 = (const float*)d_in[32];
    const float* role_g1 = (const float*)d_in[33]; const float* role_be1 = (const float*)d_in[34];
    const float* role_W2 = (const float*)d_in[35]; const float* role_b2 = (const float*)d_in[36];
    const float* rln_g = (const float*)d_in[37];   const float* rln_b = (const float*)d_in[38];
    const float* gru_Wih = (const float*)d_in[39]; const float* gru_Whh = (const float*)d_in[40];
    const float* gru_bih = (const float*)d_in[41]; const float* gru_bhh = (const float*)d_in[42];
    const float* qn_W = (const float*)d_in[43];    const float* qn_b = (const float*)d_in[44];
    const float* qp_W = (const float*)d_in[45];    const float* kp_W = (const float*)d_in[46];

    char* wsp = (char*)d_ws;
    size_t off = 0;
    auto alloc = [&](size_t bytes) { void* p = wsp + off; off = (off + bytes + 255) & ~(size_t)255; return p; };

    unsigned short* X    = (unsigned short*)alloc((size_t)MROWS * 360 * 2);
    unsigned short* XG   = (unsigned short*)alloc((size_t)MROWS * 520 * 2);
    unsigned short* FPC  = (unsigned short*)alloc((size_t)MROWS * 384 * 2);
    unsigned short* XQ   = (unsigned short*)alloc((size_t)MROWS * 264 * 2);
    unsigned short* T2b  = (unsigned short*)alloc((size_t)MROWS * 128 * 2);
    unsigned short* T3b  = (unsigned short*)alloc((size_t)MROWS * 128 * 2);
    unsigned short* QWSb = (unsigned short*)alloc((size_t)MROWS * 40 * 2);
    // composed bf16 weights
    unsigned short* FPW  = (unsigned short*)alloc(384 * 360 * 2);
    unsigned short* WGRU = (unsigned short*)alloc(1024 * 520 * 2);
    unsigned short* QWSW = (unsigned short*)alloc(40 * 264 * 2);
    unsigned short* WQKSO= (unsigned short*)alloc(256 * 32 * 2);
    unsigned short* rpW  = (unsigned short*)alloc(128 * 128 * 2);
    unsigned short* zbuf = (unsigned short*)alloc(256);
    // fp32 scratch
    float* WkAp = (float*)alloc(256 * 32 * 4);
    float* WvAp = (float*)alloc(256 * 32 * 4);
    float* WkEp = (float*)alloc(256 * 32 * 4);
    float* WvEp = (float*)alloc(256 * 32 * 4);
    float* Wkpp = (float*)alloc(256 * 32 * 4);
    float* WQKS_AE = (float*)alloc(256 * 256 * 4);
    float* WoVA = (float*)alloc(256 * 128 * 4);
    float* WoVE = (float*)alloc(256 * 128 * 4);
    float* bvAp = (float*)alloc(256 * 4);
    float* bvEp = (float*)alloc(256 * 4);
    float* bkpp = (float*)alloc(256 * 4);
    float* vall = (float*)alloc(768 * 4);
    float* qksb = (float*)alloc(256 * 4);
    float* fpb  = (float*)alloc(384 * 4);
    float* gbias= (float*)alloc(1024 * 4);
    float* rpb  = (float*)alloc(128 * 4);

    float* Qout = (float*)d_out;
    float* Hout = Qout + (size_t)MROWS * 22;

    auto tilesOf = [](const TOp& o) {
        return o.nb * (((o.I + 31) / 32) * ((o.J + 31) / 32));
    };

    // ---- prep ----
    cvt_misc<<<(MROWS * 64 + 16 + 255) / 256, 256, 0, stream>>>(hidden, XG, zbuf);

    {   // mv1
        MOpSet S; S.n = 5; int waves = 0;
        S.ops[0] = {aA_Wv, 256, ally_b, nullptr, nullptr, bvAp, 256, 256};
        S.ops[1] = {aE_Wv, 256, en_b, nullptr, nullptr, bvEp, 256, 256};
        S.ops[2] = {kp_W, 256, en_b, nullptr, nullptr, bkpp, 256, 256};
        S.ops[3] = {nullptr, 0, nullptr, own_b, nullptr, vall, 256, 0};
        S.ops[4] = {role_W1, 128, pool_b2, role_b1, nullptr, rpb, 128, 128};
        for (int i = 0; i < S.n; i++) { S.waves[i] = S.ops[i].I; waves += S.ops[i].I; }
        mv_ops<<<(waves + 3) / 4, 256, 0, stream>>>(S);
    }
    {   // T1
        TOpSet S; S.n = 0; int grid = 0;
        auto add = [&](TOp o) { S.tiles[S.n] = tilesOf(o); grid += S.tiles[S.n]; S.ops[S.n++] = o; };
        add({1, aA_Wk, 256, 1, ally_W, 1, 32, WkAp, 32, 256, 32, 256, 1, 0, 0, 0});
        add({1, aA_Wv, 256, 1, ally_W, 1, 32, WvAp, 32, 256, 32, 256, 1, 0, 0, 0});
        add({1, aE_Wk, 256, 1, en_W, 1, 32, WkEp, 32, 256, 32, 256, 1, 0, 0, 0});
        add({1, aE_Wv, 256, 1, en_W, 1, 32, WvEp, 32, 256, 32, 256, 1, 0, 0, 0});
        add({1, kp_W, 256, 1, en_W, 1, 32, Wkpp, 32, 256, 32, 256, 1, 0, 0, 0});
        compose_tiled<<<grid, 256, 0, stream>>>(S);
    }
    {   // T2
        TOpSet S; S.n = 0; int grid = 0;
        auto add = [&](TOp o) { S.tiles[S.n] = tilesOf(o); grid += S.tiles[S.n]; S.ops[S.n++] = o; };
        add({1, WkAp, 1, 32, aA_Wq, 1, 256, WQKS_AE, 256, 32, 256, 64, 4, 2048, 16384, 8192});
        add({1, WkEp, 1, 32, aE_Wq, 1, 256, WQKS_AE + 128 * 256, 256, 32, 256, 64, 4, 2048, 16384, 8192});
        add({1, aA_Wo, 256, 1, WvAp, 1, 32, WoVA, 128, 256, 32, 64, 4, 64, 2048, 32});
        add({1, aE_Wo, 256, 1, WvEp, 1, 32, WoVE, 128, 256, 32, 64, 4, 64, 2048, 32});
        compose_tiled<<<grid, 256, 0, stream>>>(S);
    }
    {   // mv2
        MOpSet S; S.n = 3; int waves = 0;
        S.ops[0] = {aA_Wo, 256, bvAp, nullptr, nullptr, vall + 256, 256, 256};
        S.ops[1] = {aE_Wo, 256, bvEp, nullptr, nullptr, vall + 512, 256, 256};
        S.ops[2] = {WQKS_AE, 256, own_b, nullptr, nullptr, qksb, 256, 256};
        for (int i = 0; i < S.n; i++) { S.waves[i] = S.ops[i].I; waves += S.ops[i].I; }
        mv_ops<<<(waves + 3) / 4, 256, 0, stream>>>(S);
    }
    {   // mv3
        MOpSet S; S.n = 5; int waves = 0;
        S.ops[0] = {fuse_W1, 768, vall, fuse_b1, nullptr, fpb, 256, 768};
        S.ops[1] = {pool_W1, 768, vall, pool_b1, nullptr, fpb + 256, 128, 256};
        S.ops[2] = {gru_Wih, 264, fuse_b2, gru_bih, gru_bhh, gbias, 512, 256};
        S.ops[3] = {gru_Wih + 512 * 264, 264, fuse_b2, gru_bih + 512, nullptr, gbias + 512, 256, 256};
        S.ops[4] = {nullptr, 0, nullptr, gru_bhh + 512, nullptr, gbias + 768, 256, 0};
        for (int i = 0; i < S.n; i++) { S.waves[i] = S.ops[i].I; waves += S.ops[i].I; }
        mv_ops<<<(waves + 3) / 4, 256, 0, stream>>>(S);
    }
    {   // T3
        TOpSet S; S.n = 0; int grid = 0;
        auto add = [&](TOp o) { S.tiles[S.n] = tilesOf(o); grid += S.tiles[S.n]; S.ops[S.n++] = o; };
        // FPW rows 0..256 (fuse)
        add({0, fuse_W1, 768, 1, own_W, 1, 32, FPW, 360, 256, 32, 256, 1, 0, 0, 0});
        add({3, nullptr, 0, 0, nullptr, 0, 0, FPW + 32, 360, 256, 72, 0, 1, 0, 0, 0});
        add({0, fuse_W1 + 256, 768, 1, WoVA, 1, 128, FPW + 104, 360, 256, 128, 256, 1, 0, 0, 0});
        add({0, fuse_W1 + 512, 768, 1, WoVE, 1, 128, FPW + 232, 360, 256, 128, 256, 1, 0, 0, 0});
        // FPW rows 256..384 (pool)
        add({0, pool_W1, 768, 1, own_W, 1, 32, FPW + 256 * 360, 360, 128, 32, 256, 1, 0, 0, 0});
        add({0, pool_W1 + 256, 768, 1, ally_W, 1, 32, FPW + 256 * 360 + 32, 360, 128, 32, 256, 1, 0, 0, 0});
        add({0, pool_W1 + 512, 768, 1, en_W, 1, 32, FPW + 256 * 360 + 64, 360, 128, 32, 256, 1, 0, 0, 0});
        add({0, pool_W1 + 256, 768, 1, ally_b, 0, 1, FPW + 256 * 360 + 96, 360, 128, 1, 256, 1, 0, 0, 0});
        add({0, pool_W1 + 512, 768, 1, en_b, 0, 1, FPW + 256 * 360 + 97, 360, 128, 1, 256, 1, 0, 0, 0});
        add({3, nullptr, 0, 0, nullptr, 0, 0, FPW + 256 * 360 + 98, 360, 128, 262, 0, 1, 0, 0, 0});
        // WGRU rows 0..512 (r,z)
        add({0, gru_Wih, 264, 1, fuse_W2, 1, 256, WGRU, 520, 512, 256, 256, 1, 0, 0, 0});
        add({2, gru_Wih + 256, 264, 1, nullptr, 0, 0, WGRU + 256, 520, 512, 8, 0, 1, 0, 0, 0});
        add({2, gru_Whh, 256, 1, nullptr, 0, 0, WGRU + 264, 520, 512, 256, 0, 1, 0, 0, 0});
        // WGRU rows 512..768 (i_n)
        add({0, gru_Wih + 512 * 264, 264, 1, fuse_W2, 1, 256, WGRU + 512 * 520, 520, 256, 256, 256, 1, 0, 0, 0});
        add({2, gru_Wih + 512 * 264 + 256, 264, 1, nullptr, 0, 0, WGRU + 512 * 520 + 256, 520, 256, 8, 0, 1, 0, 0, 0});
        add({3, nullptr, 0, 0, nullptr, 0, 0, WGRU + 512 * 520 + 264, 520, 256, 256, 0, 1, 0, 0, 0});
        // WGRU rows 768..1024 (h_n)
        add({3, nullptr, 0, 0, nullptr, 0, 0, WGRU + 768 * 520, 520, 256, 264, 0, 1, 0, 0, 0});
        add({2, gru_Whh + 512 * 256, 256, 1, nullptr, 0, 0, WGRU + 768 * 520 + 264, 520, 256, 256, 0, 1, 0, 0, 0});
        // QWSW
        add({0, Wkpp, 1, 32, qp_W, 1, 264, QWSW, 264, 32, 264, 256, 1, 0, 0, 0});
        add({0, bkpp, 0, 1, qp_W, 1, 264, QWSW + 32 * 264, 264, 1, 264, 256, 1, 0, 0, 0});
        add({2, qn_W, 256, 1, nullptr, 0, 0, QWSW + 33 * 264, 264, 6, 256, 0, 1, 0, 0, 0});
        add({3, nullptr, 0, 0, nullptr, 0, 0, QWSW + 33 * 264 + 256, 264, 6, 8, 0, 1, 0, 0, 0});
        add({3, nullptr, 0, 0, nullptr, 0, 0, QWSW + 39 * 264, 264, 1, 264, 0, 1, 0, 0, 0});
        // WQKSO bf16
        add({0, WQKS_AE, 256, 1, own_W, 1, 32, WQKSO, 32, 256, 32, 256, 1, 0, 0, 0});
        // rpW = role_W1 @ pool_W2
        add({0, role_W1, 128, 1, pool_W2, 1, 128, rpW, 128, 128, 128, 128, 1, 0, 0, 0});
        compose_tiled<<<grid, 256, 0, stream>>>(S);
    }

    auto gemm = [&](const unsigned short* A, int lda, const unsigned short* Wm, const float* bias,
                    unsigned short* C, int ldc, int N, int K, int act) {
        gemm_bf16<64, 64><<<dim3(MROWS / 64, (N + 63) / 64), 256, 0, stream>>>(
            A, lda, Wm, bias, C, ldc, N, K, act, zbuf);
    };

    // ---- main chain ----
    glue_attn<<<MROWS / 4, 256, 0, stream>>>(ally_feats, enemy_feats, own_feats, WQKSO, qksb, X);
    gemm(X, 360, FPW, fpb, FPC, 384, 384, 360, 1);                    // fuse1+pool1 (+gelu)
    ln_fp<<<MROWS / 4, 256, 0, stream>>>(FPC, fuse_g1, fuse_be1, pool_g1, pool_be1, XG, T2b);
    gemm(T2b, 128, rpW, rpb, T3b, 128, 128, 128, 1);                  // role1 (pool_W2 folded) + gelu
    ln_role<<<MROWS / 32, 256, 0, stream>>>(T3b, role_g1, role_be1, role_W2, role_b2, rln_g, rln_b, XG, XQ);
    gemm_gru<<<dim3(MROWS / 64, 4), 512, 0, stream>>>(XG, 520, WGRU, gbias, hidden,
                                                      Hout, XQ, 520, zbuf);   // fused GRU (8-wave)
    gemm(XQ, 264, QWSW, nullptr, QWSb, 40, 40, 264, 0);               // qws + c0 + q_normal
    glue_final<<<MROWS / 8, 256, 0, stream>>>(QWSb, enemy_feats, qn_b, Qout);
}

// Round 10
// 410.878 us; speedup vs baseline: 1.0252x; 1.0252x over previous
//
#include <hip/hip_runtime.h>
#include <hip/hip_bf16.h>

// CAPERNN_ContRoles_HPN — round 14: revert QKS-fusion (cost +24us in glue_attn: VGPR 60,
// occupancy 37%, 266K bank conflicts, serial 128-FMA chain), restore round-12 glue_attn +
// standalone QKS gemm. KEEP 8-wave gemm_gru (arithmetic suggests 51 -> ~44us).
// M = BN = 16384, H=256, NH=4, HD=64, NA=15, NE=16, RD=8, NMOVE=6.

#define MROWS 16384

typedef __attribute__((ext_vector_type(8))) short short8;
typedef __attribute__((ext_vector_type(4))) float float4v;
typedef __attribute__((ext_vector_type(4))) unsigned short ushort4v;
typedef __attribute__((ext_vector_type(2))) unsigned short ushort2v;

__device__ __forceinline__ unsigned short f2b(float f) {
    __hip_bfloat16 h = __float2bfloat16(f);
    return *reinterpret_cast<unsigned short*>(&h);
}
__device__ __forceinline__ float b2f(unsigned short u) {
    __hip_bfloat16 h;
    *reinterpret_cast<unsigned short*>(&h) = u;
    return __bfloat162float(h);
}
__device__ __forceinline__ void gll16(const unsigned short* g, unsigned short* l) {
    __builtin_amdgcn_global_load_lds((const __attribute__((address_space(1))) void*)g,
                                     (__attribute__((address_space(3))) void*)l, 16, 0, 0);
}

// ---------------- prep: hidden->XG[264:520], own->OWNb, zero zbuf ----------------
__global__ void cvt_misc(const float* __restrict__ hidden, const float* __restrict__ ownf,
                         unsigned short* __restrict__ XG, unsigned short* __restrict__ OWNb,
                         unsigned short* __restrict__ zbuf) {
    int idx = blockIdx.x * 256 + threadIdx.x;
    const int nh = MROWS * 64;        // hidden: 4 elems/thread
    const int no = MROWS * 8;         // own: 4 elems/thread
    if (idx < nh) {
        int row = idx >> 6, c4 = (idx & 63) * 4;
        float4 v = *(const float4*)(hidden + (size_t)row * 256 + c4);
        ushort4v d = { f2b(v.x), f2b(v.y), f2b(v.z), f2b(v.w) };
        *(ushort4v*)(XG + (size_t)row * 520 + 264 + c4) = d;
    } else if (idx < nh + no) {
        int j = idx - nh;
        int row = j >> 3, c4 = (j & 7) * 4;
        float4 v = *(const float4*)(ownf + (size_t)row * 32 + c4);
        ushort4v d = { f2b(v.x), f2b(v.y), f2b(v.z), f2b(v.w) };
        *(ushort4v*)(OWNb + (size_t)row * 32 + c4) = d;
    } else if (idx < nh + no + 16) {
        int j = idx - nh - no;
        ((uint4*)zbuf)[j] = make_uint4(0u, 0u, 0u, 0u);   // 256 B zeros
    }
}

// ---------------- tiled compose: 32x32 output tiles, LDS-staged ----------------
// type 0: matmul->bf16, 1: matmul->fp32, 2: cvt copy->bf16, 3: zero bf16
struct TOp {
    int type;
    const float* A; int sAi, sAk;
    const float* B; int sBj, sBk;
    void* O; int sOi;
    int I, J, K;
    int nb; int aB, bB, oB;
};
struct TOpSet { int n; int tiles[26]; TOp ops[26]; };

__global__ __launch_bounds__(256)
void compose_tiled(TOpSet S) {
    int t = blockIdx.x;
    int op = 0;
    while (op < S.n && t >= S.tiles[op]) { t -= S.tiles[op]; op++; }
    if (op >= S.n) return;
    TOp o = S.ops[op];
    int ti = (o.I + 31) >> 5, tj = (o.J + 31) >> 5;
    int per = ti * tj;
    int b = t / per;
    int rem = t - b * per;
    int i0 = (rem / tj) * 32, j0 = (rem % tj) * 32;
    int tid = threadIdx.x;
    if (o.type >= 2) {
        for (int e = tid; e < 1024; e += 256) {
            int r = e >> 5, c = e & 31;
            int i = i0 + r, j = j0 + c;
            if (i < o.I && j < o.J) {
                unsigned short v = 0;
                if (o.type == 2) v = f2b(o.A[(long)b * o.aB + (long)i * o.sAi + (long)j * o.sAk]);
                ((unsigned short*)o.O)[(long)b * o.oB + (long)i * o.sOi + j] = v;
            }
        }
        return;
    }
    __shared__ float As[32][33];
    __shared__ float Bs[32][33];
    int tx = tid & 15, ty = tid >> 4;
    float a00 = 0.f, a01 = 0.f, a10 = 0.f, a11 = 0.f;
    const float* Ab = o.A + (long)b * o.aB;
    const float* Bb = o.B + (long)b * o.bB;
    for (int k0 = 0; k0 < o.K; k0 += 32) {
        for (int e = tid; e < 1024; e += 256) {
            int r = e >> 5, c = e & 31;
            As[r][c] = (i0 + r < o.I && k0 + c < o.K)
                       ? Ab[(long)(i0 + r) * o.sAi + (long)(k0 + c) * o.sAk] : 0.f;
            Bs[r][c] = (k0 + r < o.K && j0 + c < o.J)
                       ? Bb[(long)(j0 + c) * o.sBj + (long)(k0 + r) * o.sBk] : 0.f;
        }
        __syncthreads();
#pragma unroll
        for (int k = 0; k < 32; k++) {
            float x0 = As[ty * 2][k], x1 = As[ty * 2 + 1][k];
            float y0 = Bs[k][tx * 2], y1 = Bs[k][tx * 2 + 1];
            a00 += x0 * y0; a01 += x0 * y1; a10 += x1 * y0; a11 += x1 * y1;
        }
        __syncthreads();
    }
    int i = i0 + ty * 2, j = j0 + tx * 2;
    float vals[2][2] = {{a00, a01}, {a10, a11}};
#pragma unroll
    for (int di = 0; di < 2; di++)
#pragma unroll
        for (int dj = 0; dj < 2; dj++) {
            int ii = i + di, jj = j + dj;
            if (ii < o.I && jj < o.J) {
                long oidx = (long)b * o.oB + (long)ii * o.sOi + jj;
                if (o.type == 0) ((unsigned short*)o.O)[oidx] = f2b(vals[di][dj]);
                else ((float*)o.O)[oidx] = vals[di][dj];
            }
        }
}

// ---------------- matvec ops: one wave per output ----------------
struct MOp { const float* A; int sAi; const float* x; const float* b1; const float* b2; float* out; int I, K; };
struct MOpSet { int n; int waves[10]; MOp ops[10]; };

__global__ void mv_ops(MOpSet S) {
    int wid = blockIdx.x * 4 + (threadIdx.x >> 6);
    int lane = threadIdx.x & 63;
    int op = 0;
    while (op < S.n && wid >= S.waves[op]) { wid -= S.waves[op]; op++; }
    if (op >= S.n) return;
    MOp o = S.ops[op];
    float s = 0.f;
    for (int k = lane; k < o.K; k += 64) s += o.A[(long)wid * o.sAi + k] * o.x[k];
    for (int off = 32; off; off >>= 1) s += __shfl_xor(s, off, 64);
    if (lane == 0) {
        if (o.b1) s += o.b1[wid];
        if (o.b2) s += o.b2[wid];
        o.out[wid] = s;
    }
}

// ---------------- bf16 MFMA GEMM: C[MxN] = A[MxK] @ W[NxK]^T (+bias)(+gelu) ----------------
// Round-11 config: 64x64 tile, 4 waves 2x2, BK=32, 2-buf LDS (16KB), round-7 step scheme.
template<int BM, int BN>
__global__ __launch_bounds__(256, 4)
void gemm_bf16(const unsigned short* __restrict__ A, int lda,
               const unsigned short* __restrict__ W,
               const float* __restrict__ bias,
               unsigned short* __restrict__ C, int ldc,
               int N, int K, int act,
               const unsigned short* __restrict__ zbuf) {
    constexpr int MI = BM / 32, NJ = BN / 32;
    __shared__ __align__(16) unsigned short As[2][BM * 32];
    __shared__ __align__(16) unsigned short Bs[2][BN * 32];
    int tid = threadIdx.x;
    int m0 = blockIdx.x * BM, n0 = blockIdx.y * BN;
    int wave = tid >> 6, lane = tid & 63;
    int wm = (wave & 1) * (BM / 2), wn = (wave >> 1) * (BN / 2);
    int l16 = lane & 15, quad = lane >> 4;

    float4v acc[MI][NJ];
#pragma unroll
    for (int i = 0; i < MI; i++)
#pragma unroll
        for (int j = 0; j < NJ; j++) acc[i][j] = (float4v){0.f, 0.f, 0.f, 0.f};

    int swz = ((l16 >> 1) & 3) * 8;
    int nt = (K + 31) >> 5;

    auto stage = [&](int buf, int k0) {
#pragma unroll
        for (int s0 = 0; s0 < BM * 4; s0 += 256) {
            int s = s0 + tid;
            int row = s >> 2;
            int cg = (s & 3) ^ ((row >> 1) & 3);
            int ka = k0 + cg * 8;
            gll16((ka < K) ? A + (size_t)(m0 + row) * lda + ka : zbuf, &As[buf][s * 8]);
        }
#pragma unroll
        for (int s0 = 0; s0 < BN * 4; s0 += 256) {
            int s = s0 + tid;
            int row = s >> 2;
            int cg = (s & 3) ^ ((row >> 1) & 3);
            int ka = k0 + cg * 8;
            gll16((ka < K && n0 + row < N) ? W + (size_t)(n0 + row) * K + ka : zbuf,
                  &Bs[buf][s * 8]);
        }
    };
    auto compute = [&](int buf) {
        short8 a[MI], b[NJ];
#pragma unroll
        for (int i = 0; i < MI; i++)
            a[i] = *(const short8*)(&As[buf][(wm + i * 16 + l16) * 32 + ((quad * 8) ^ swz)]);
#pragma unroll
        for (int j = 0; j < NJ; j++)
            b[j] = *(const short8*)(&Bs[buf][(wn + j * 16 + l16) * 32 + ((quad * 8) ^ swz)]);
#pragma unroll
        for (int i = 0; i < MI; i++)
#pragma unroll
            for (int j = 0; j < NJ; j++)
                acc[i][j] = __builtin_amdgcn_mfma_f32_16x16x32_bf16(a[i], b[j], acc[i][j], 0, 0, 0);
    };

    stage(0, 0);
    asm volatile("s_waitcnt vmcnt(0)" ::: "memory");
    __builtin_amdgcn_s_barrier();
    for (int t = 0; t < nt - 1; t++) {
        stage((t + 1) & 1, (t + 1) << 5);   // next tile in flight during compute
        compute(t & 1);
        asm volatile("s_waitcnt vmcnt(0)" ::: "memory");
        __builtin_amdgcn_s_barrier();
    }
    compute((nt - 1) & 1);

#pragma unroll
    for (int i = 0; i < MI; i++) {
#pragma unroll
        for (int j = 0; j < NJ; j++) {
#pragma unroll
            for (int rr = 0; rr < 4; rr++) {
                int rowm = m0 + wm + i * 16 + quad * 4 + rr;
                int coln = wn + j * 16 + l16;
                if (n0 + coln >= N) continue;
                float v = acc[i][j][rr];
                if (bias) v += bias[n0 + coln];
                if (act == 1) v = 0.5f * v * (1.f + erff(v * 0.70710678f));
                C[(size_t)rowm * ldc + n0 + coln] = f2b(v);
            }
        }
    }
}

// ---------------- 4-gate fused GRU GEMM + nonlinearity, 8 waves (512 threads) ----------------
// Wave w: rows [wm=(w&3)*16, +16), cols [wn=(w>>2)*32, +32) of ALL 4 gates -> acc[4][2].
// 4 blocks/CU x 8 waves = 32 waves/CU (LDS 4x40KB=160KB, threads 4x512=2048: exact fill).
__global__ __launch_bounds__(512, 4)
void gemm_gru(const unsigned short* __restrict__ A, int lda,        // XG, lda=520
              const unsigned short* __restrict__ W,                 // WGRU [1024][520]
              const float* __restrict__ gbias,                      // [1024]
              const float* __restrict__ hp,                         // h_prev f32 [M][256]
              float* __restrict__ hout, unsigned short* __restrict__ XQ,
              int K, const unsigned short* __restrict__ zbuf) {
    __shared__ __align__(16) unsigned short As[2][64 * 32];
    __shared__ __align__(16) unsigned short Ws[2][4 * 64 * 32];
    int tid = threadIdx.x;
    int m0 = blockIdx.x * 64, n0 = blockIdx.y * 64;
    int wave = tid >> 6, lane = tid & 63;
    int wm = (wave & 3) * 16, wn = (wave >> 2) * 32;
    int l16 = lane & 15, quad = lane >> 4;

    float4v acc[4][2];
#pragma unroll
    for (int g = 0; g < 4; g++)
#pragma unroll
        for (int j = 0; j < 2; j++) acc[g][j] = (float4v){0.f, 0.f, 0.f, 0.f};

    int swz = ((l16 >> 1) & 3) * 8;
    int nt = (K + 31) >> 5;

    // staging: A slots 0..255 (threads < 256), W slots 0..1023 (2 per thread)
    const unsigned short* Aptr = A;   // only valid for tid<256
    int aKoff = 0;
    if (tid < 256) {
        int row = tid >> 2;
        int cg = (tid & 3) ^ ((row >> 1) & 3);
        Aptr = A + (size_t)(m0 + row) * lda + cg * 8;
        aKoff = cg * 8;
    }
    const unsigned short* Wptr[2];
    int wKoff[2];
    int wSlot0 = tid, wSlot1 = tid + 512;
    {
        int s = wSlot0;
        int g = s >> 8, s8 = s & 255;
        int row = s8 >> 2;
        int cg = (s8 & 3) ^ ((row >> 1) & 3);
        Wptr[0] = W + (size_t)(g * 256 + n0 + row) * K + cg * 8;
        wKoff[0] = cg * 8;
        s = wSlot1;
        g = s >> 8; s8 = s & 255;
        row = s8 >> 2;
        cg = (s8 & 3) ^ ((row >> 1) & 3);
        Wptr[1] = W + (size_t)(g * 256 + n0 + row) * K + cg * 8;
        wKoff[1] = cg * 8;
    }

    auto stage = [&](int buf, int k0) {
        if (tid < 256)
            gll16((k0 + aKoff < K) ? Aptr + k0 : zbuf, &As[buf][tid * 8]);
        gll16((k0 + wKoff[0] < K) ? Wptr[0] + k0 : zbuf, &Ws[buf][wSlot0 * 8]);
        gll16((k0 + wKoff[1] < K) ? Wptr[1] + k0 : zbuf, &Ws[buf][wSlot1 * 8]);
    };
    auto compute = [&](int buf) {
        short8 a = *(const short8*)(&As[buf][(wm + l16) * 32 + ((quad * 8) ^ swz)]);
        short8 b[4][2];
#pragma unroll
        for (int g = 0; g < 4; g++)
#pragma unroll
            for (int j = 0; j < 2; j++)
                b[g][j] = *(const short8*)(&Ws[buf][g * 2048 + (wn + j * 16 + l16) * 32 + ((quad * 8) ^ swz)]);
#pragma unroll
        for (int g = 0; g < 4; g++)
#pragma unroll
            for (int j = 0; j < 2; j++)
                acc[g][j] = __builtin_amdgcn_mfma_f32_16x16x32_bf16(a, b[g][j], acc[g][j], 0, 0, 0);
    };

    stage(0, 0);
    asm volatile("s_waitcnt vmcnt(0)" ::: "memory");
    __builtin_amdgcn_s_barrier();
    for (int t = 0; t < nt - 1; t++) {
        stage((t + 1) & 1, (t + 1) << 5);
        compute(t & 1);
        asm volatile("s_waitcnt vmcnt(0)" ::: "memory");
        __builtin_amdgcn_s_barrier();
    }
    compute((nt - 1) & 1);

#pragma unroll
    for (int j = 0; j < 2; j++) {
#pragma unroll
        for (int rr = 0; rr < 4; rr++) {
            int rowm = m0 + wm + quad * 4 + rr;
            int coln = n0 + wn + j * 16 + l16;            // h-column 0..255
            float r_ = acc[0][j][rr] + gbias[coln];
            float z_ = acc[1][j][rr] + gbias[256 + coln];
            float in_ = acc[2][j][rr] + gbias[512 + coln];
            float hn_ = acc[3][j][rr] + gbias[768 + coln];
            float rg = 1.f / (1.f + __expf(-r_));
            float zg = 1.f / (1.f + __expf(-z_));
            float ng = tanhf(in_ + rg * hn_);
            float h = (1.f - zg) * ng + zg * hp[(size_t)rowm * 256 + coln];
            hout[(size_t)rowm * 256 + coln] = h;
            XQ[(size_t)rowm * 264 + coln] = f2b(h);
        }
    }
}

// ---------------- combined LN: FPC[:,0:256]->XG(ld520), FPC[:,256:384]->T2 ----------------
__global__ __launch_bounds__(256)
void ln_fp(const unsigned short* __restrict__ FPC,
           const float* __restrict__ g1, const float* __restrict__ be1,
           const float* __restrict__ g2, const float* __restrict__ be2,
           unsigned short* __restrict__ XG, unsigned short* __restrict__ T2) {
    int tid = threadIdx.x;
    size_t row = (size_t)blockIdx.x * 4 + (tid >> 6);
    int l = tid & 63;
    const unsigned short* src = FPC + row * 384;
    ushort4v vf = *(const ushort4v*)(src + l * 4);
    ushort2v vp = *(const ushort2v*)(src + 256 + l * 2);
    float f0 = b2f(vf[0]), f1 = b2f(vf[1]), f2v = b2f(vf[2]), f3 = b2f(vf[3]);
    float p0 = b2f(vp[0]), p1 = b2f(vp[1]);
    float s = f0 + f1 + f2v + f3;
    float q = f0 * f0 + f1 * f1 + f2v * f2v + f3 * f3;
    float s2 = p0 + p1, q2 = p0 * p0 + p1 * p1;
    for (int o = 32; o; o >>= 1) {
        s += __shfl_xor(s, o, 64); q += __shfl_xor(q, o, 64);
        s2 += __shfl_xor(s2, o, 64); q2 += __shfl_xor(q2, o, 64);
    }
    float mean = s * (1.f / 256.f);
    float rstd = rsqrtf(q * (1.f / 256.f) - mean * mean + 1e-5f);
    float4 g = *(const float4*)(g1 + l * 4);
    float4 be = *(const float4*)(be1 + l * 4);
    ushort4v o4;
    o4[0] = f2b((f0 - mean) * rstd * g.x + be.x);
    o4[1] = f2b((f1 - mean) * rstd * g.y + be.y);
    o4[2] = f2b((f2v - mean) * rstd * g.z + be.z);
    o4[3] = f2b((f3 - mean) * rstd * g.w + be.w);
    *(ushort4v*)(XG + row * 520 + l * 4) = o4;
    float mean2 = s2 * (1.f / 128.f);
    float rstd2 = rsqrtf(q2 * (1.f / 128.f) - mean2 * mean2 + 1e-5f);
    float2 gg = *(const float2*)(g2 + l * 2);
    float2 bb = *(const float2*)(be2 + l * 2);
    ushort2v o2;
    o2[0] = f2b((p0 - mean2) * rstd2 * gg.x + bb.x);
    o2[1] = f2b((p1 - mean2) * rstd2 * gg.y + bb.y);
    *(ushort2v*)(T2 + row * 128 + l * 2) = o2;
}

// ---------------- attention glue: softmax + weighted feats + means (4 rows/block) ----------------
// entity stride 36 floats (16B-aligned, 2-way-bank free), float4 staging, b128 score dots
__global__ __launch_bounds__(256)
void glue_attn(const float* __restrict__ allyf, const float* __restrict__ enemyf,
               const float* __restrict__ ownf, const unsigned short* __restrict__ QKS,
               unsigned short* __restrict__ X) {
    __shared__ __align__(16) float af[4][540];    // 15 x 36
    __shared__ __align__(16) float ef[4][576];    // 16 x 36
    __shared__ __align__(16) float qk[4][288];    // 8 head-chunks x 36
    __shared__ float attnA[4][64];
    __shared__ float attnE[4][64];
    __shared__ float mskA[4][16];
    __shared__ float mskE[4][16];
    int tid = threadIdx.x;
    size_t rb = (size_t)blockIdx.x * 4;

    for (int idx = tid; idx < 480; idx += 256) {          // ally: 120 float4 / row
        int r = idx / 120, ch = idx - r * 120;
        float4 v = *(const float4*)(allyf + ((rb + r) * 480 + ch * 4));
        *(float4*)&af[r][(ch >> 3) * 36 + (ch & 7) * 4] = v;
    }
    for (int idx = tid; idx < 512; idx += 256) {          // enemy: 128 float4 / row
        int r = idx >> 7, ch = idx & 127;
        float4 v = *(const float4*)(enemyf + ((rb + r) * 512 + ch * 4));
        *(float4*)&ef[r][(ch >> 3) * 36 + (ch & 7) * 4] = v;
    }
    if (tid < 128) {                                       // qks: 32 short8 / row
        int r = tid >> 5, ch = tid & 31;
        short8 v = *(const short8*)(QKS + (rb + r) * 256 + ch * 8);
#pragma unroll
        for (int j = 0; j < 8; j++)
            qk[r][(ch >> 2) * 36 + (ch & 3) * 8 + j] = b2f((unsigned short)v[j]);
    } else {                                               // own copy: 4 x 32 cols
        int r = (tid - 128) >> 5, c = (tid - 128) & 31;
        X[(rb + r) * 360 + c] = f2b(ownf[(rb + r) * 32 + c]);
    }
    if (tid < 24) {
        int r = tid / 6, c = 98 + tid % 6;
        X[(rb + r) * 360 + c] = 0;
    }
    __syncthreads();

    // masks: 2 lanes per (row, entity), float4 scans + pair shfl
    if (tid < 248) {
        int pair = tid >> 1, half = tid & 1;
        int r = pair / 31, e = pair - r * 31;
        const float* base = (e < 15) ? &af[r][e * 36] : &ef[r][(e - 15) * 36];
        const float4* b4 = (const float4*)base + half * 4;
        bool nz = false;
#pragma unroll
        for (int k = 0; k < 4; k++) {
            float4 v = b4[k];
            nz |= (v.x != 0.f) || (v.y != 0.f) || (v.z != 0.f) || (v.w != 0.f);
        }
        int other = __shfl_xor((int)nz, 1, 64);
        float mv = (nz || other != 0) ? 1.f : 0.f;
        if (half == 0) {
            if (e < 15) mskA[r][e] = mv; else mskE[r][e - 15] = mv;
        }
    } else if (tid < 252) {
        mskA[tid - 248][15] = 0.f;
    }
    __syncthreads();

    int r = tid >> 6, lane = tid & 63;
    int h = lane >> 4, m = lane & 15;
    // ally softmax (15 entities)
    {
        float sc = -3.0e38f;
        if (m < 15) {
            const float4* qa = (const float4*)&qk[r][h * 36];
            const float4* aa = (const float4*)&af[r][m * 36];
            float s = 0.f;
#pragma unroll
            for (int k = 0; k < 8; k++) {
                float4 q = qa[k], a = aa[k];
                s += q.x * a.x + q.y * a.y + q.z * a.z + q.w * a.w;
            }
            sc = (mskA[r][m] > 0.f) ? s * 0.125f : -1e9f;
        }
        float mx = sc;
        for (int o = 8; o; o >>= 1) mx = fmaxf(mx, __shfl_xor(mx, o, 64));
        float e = (m < 15) ? __expf(sc - mx) : 0.f;
        float sm = e;
        for (int o = 8; o; o >>= 1) sm += __shfl_xor(sm, o, 64);
        attnA[r][h * 16 + m] = e / sm;
    }
    // enemy softmax (16 entities)
    {
        const float4* qa = (const float4*)&qk[r][(4 + h) * 36];
        const float4* aa = (const float4*)&ef[r][m * 36];
        float s = 0.f;
#pragma unroll
        for (int k = 0; k < 8; k++) {
            float4 q = qa[k], a = aa[k];
            s += q.x * a.x + q.y * a.y + q.z * a.z + q.w * a.w;
        }
        float sc = (mskE[r][m] > 0.f) ? s * 0.125f : -1e9f;
        float mx = sc;
        for (int o = 8; o; o >>= 1) mx = fmaxf(mx, __shfl_xor(mx, o, 64));
        float e = __expf(sc - mx);
        float sm = e;
        for (int o = 8; o; o >>= 1) sm += __shfl_xor(sm, o, 64);
        attnE[r][h * 16 + m] = e / sm;
    }
    __syncthreads();
    size_t row = rb + r;
#pragma unroll
    for (int it = 0; it < 2; it++) {
        int idx = lane + it * 64;
        int hh = idx >> 5, c = idx & 31;
        float sA = 0.f;
        for (int mm = 0; mm < 15; mm++) sA += attnA[r][hh * 16 + mm] * af[r][mm * 36 + c];
        X[row * 360 + 104 + idx] = f2b(sA);
        float sE = 0.f;
        for (int mm = 0; mm < 16; mm++) sE += attnE[r][hh * 16 + mm] * ef[r][mm * 36 + c];
        X[row * 360 + 232 + idx] = f2b(sE);
    }
    if (lane < 32) {
        float cnt = 0.f;
        for (int mm = 0; mm < 15; mm++) cnt += mskA[r][mm];
        float s = 0.f;
        for (int mm = 0; mm < 15; mm++) s += af[r][mm * 36 + lane];
        X[row * 360 + 32 + lane] = f2b(s / fmaxf(cnt, 1e-8f));
        if (lane == 0) X[row * 360 + 96] = f2b(cnt > 0.f ? 1.f : 0.f);
    } else {
        int c = lane - 32;
        float cnt = 0.f;
        for (int mm = 0; mm < 16; mm++) cnt += mskE[r][mm];
        float s = 0.f;
        for (int mm = 0; mm < 16; mm++) s += ef[r][mm * 36 + c];
        X[row * 360 + 64 + c] = f2b(s / fmaxf(cnt, 1e-8f));
        if (c == 0) X[row * 360 + 97] = f2b(cnt > 0.f ? 1.f : 0.f);
    }
}

// ---------------- fused LN(128) + role head -> XG cols 256..264 (+ XQ copy) ----------------
__global__ __launch_bounds__(256)
void ln_role(const unsigned short* __restrict__ T3, const float* __restrict__ g1,
             const float* __restrict__ be1, const float* __restrict__ W2,
             const float* __restrict__ b2, const float* __restrict__ rg,
             const float* __restrict__ rb, unsigned short* __restrict__ XG,
             unsigned short* __restrict__ XQ) {
    __shared__ float t3[32][132];
    __shared__ float gl[128], bl[128];
    int tid = threadIdx.x;
    size_t base = (size_t)blockIdx.x * 4096;
    for (int idx = tid; idx < 4096; idx += 256)
        t3[idx >> 7][idx & 127] = b2f(T3[base + idx]);
    if (tid < 128) { gl[tid] = g1[tid]; bl[tid] = be1[tid]; }
    __syncthreads();
    int r = tid >> 3, t = tid & 7;
    float s = 0.f, q = 0.f;
    for (int c = 0; c < 16; c++) { float v = t3[r][t * 16 + c]; s += v; q += v * v; }
    for (int o = 4; o; o >>= 1) { s += __shfl_xor(s, o, 8); q += __shfl_xor(q, o, 8); }
    float mean = s * (1.f / 128.f);
    float var = q * (1.f / 128.f) - mean * mean;
    float rstd = rsqrtf(var + 1e-5f);
    float acc = b2[t];
    const float* w = W2 + t * 128;
    for (int d = 0; d < 128; d++)
        acc += w[d] * ((t3[r][d] - mean) * rstd * gl[d] + bl[d]);
    float v = tanhf(acc);
    float mn = v;
    for (int o = 4; o; o >>= 1) mn += __shfl_xor(mn, o, 8);
    mn *= 0.125f;
    float dv = v - mn, qq = dv * dv;
    for (int o = 4; o; o >>= 1) qq += __shfl_xor(qq, o, 8);
    qq *= 0.125f;
    size_t row = (size_t)blockIdx.x * 32 + r;
    unsigned short ov = f2b(dv * rsqrtf(qq + 1e-5f) * rg[t] + rb[t]);
    XG[row * 520 + 256 + t] = ov;
    XQ[row * 264 + 256 + t] = ov;
}

// ---------------- final heads ----------------
__global__ __launch_bounds__(256)
void glue_final(const unsigned short* __restrict__ QWS, const float* __restrict__ efeats,
                const float* __restrict__ qnb, float* __restrict__ Q) {
    __shared__ __align__(16) float ef[8][576];   // 16 x 36
    __shared__ __align__(16) float qw[8][40];
    int tid = threadIdx.x;
    size_t rb = (size_t)blockIdx.x * 8;
    for (int idx = tid; idx < 1024; idx += 256) {        // 128 float4 / row
        int r = idx >> 7, ch = idx & 127;
        float4 v = *(const float4*)(efeats + (rb + r) * 512 + ch * 4);
        *(float4*)&ef[r][(ch >> 3) * 36 + (ch & 7) * 4] = v;
    }
    for (int idx = tid; idx < 320; idx += 256) {
        int r = idx / 40, c = idx % 40;
        qw[r][c] = b2f(QWS[(rb + r) * 40 + c]);
    }
    __syncthreads();
    int r = tid >> 5, t = tid & 31;
    size_t row = rb + r;
    float lg = 0.f, mk = 0.f;
    if (t < 16) {
        const float4* fr = (const float4*)&ef[r][t * 36];
        const float4* qv = (const float4*)&qw[r][0];
        bool nz = false;
        float s = 0.f;
#pragma unroll
        for (int k = 0; k < 8; k++) {
            float4 a = fr[k], b = qv[k];
            nz |= (a.x != 0.f) || (a.y != 0.f) || (a.z != 0.f) || (a.w != 0.f);
            s += a.x * b.x + a.y * b.y + a.z * b.z + a.w * b.w;
        }
        mk = nz ? 1.f : 0.f;
        lg = (s + qw[r][32]) * 0.0625f;
    }
    float sv = mk * lg, cv = mk;
    for (int o = 8; o; o >>= 1) { sv += __shfl_xor(sv, o, 64); cv += __shfl_xor(cv, o, 64); }
    float mean = sv / fmaxf(cv, 1.f);
    if (t < 16) Q[row * 22 + 6 + t] = (mk > 0.f ? lg : -1e9f) - mean;
    if (t < 6) Q[row * 22 + t] = qw[r][33 + t] + qnb[t];
}

// ---------------- host orchestration ----------------
extern "C" void kernel_launch(void* const* d_in, const int* in_sizes, int n_in,
                              void* d_out, int out_size, void* d_ws, size_t ws_size,
                              hipStream_t stream) {
    const float* own_feats = (const float*)d_in[1];
    const float* ally_feats = (const float*)d_in[2];
    const float* enemy_feats = (const float*)d_in[3];
    const float* hidden = (const float*)d_in[4];
    const float* own_W = (const float*)d_in[5];   const float* own_b = (const float*)d_in[6];
    const float* ally_W = (const float*)d_in[7];  const float* ally_b = (const float*)d_in[8];
    const float* en_W = (const float*)d_in[9];    const float* en_b = (const float*)d_in[10];
    const float* aA_Wq = (const float*)d_in[11];  const float* aA_Wk = (const float*)d_in[12];
    const float* aA_Wv = (const float*)d_in[13];  const float* aA_Wo = (const float*)d_in[14];
    const float* aE_Wq = (const float*)d_in[15];  const float* aE_Wk = (const float*)d_in[16];
    const float* aE_Wv = (const float*)d_in[17];  const float* aE_Wo = (const float*)d_in[18];
    const float* fuse_W1 = (const float*)d_in[19]; const float* fuse_b1 = (const float*)d_in[20];
    const float* fuse_g1 = (const float*)d_in[21]; const float* fuse_be1 = (const float*)d_in[22];
    const float* fuse_W2 = (const float*)d_in[23]; const float* fuse_b2 = (const float*)d_in[24];
    const float* pool_W1 = (const float*)d_in[25]; const float* pool_b1 = (const float*)d_in[26];
    const float* pool_g1 = (const float*)d_in[27]; const float* pool_be1 = (const float*)d_in[28];
    const float* pool_W2 = (const float*)d_in[29]; const float* pool_b2 = (const float*)d_in[30];
    const float* role_W1 = (const float*)d_in[31]; const float* role_b1 = (const float*)d_in[32];
    const float* role_g1 = (const float*)d_in[33]; const float* role_be1 = (const float*)d_in[34];
    const float* role_W2 = (const float*)d_in[35]; const float* role_b2 = (const float*)d_in[36];
    const float* rln_g = (const float*)d_in[37];   const float* rln_b = (const float*)d_in[38];
    const float* gru_Wih = (const float*)d_in[39]; const float* gru_Whh = (const float*)d_in[40];
    const float* gru_bih = (const float*)d_in[41]; const float* gru_bhh = (const float*)d_in[42];
    const float* qn_W = (const float*)d_in[43];    const float* qn_b = (const float*)d_in[44];
    const float* qp_W = (const float*)d_in[45];    const float* kp_W = (const float*)d_in[46];

    char* wsp = (char*)d_ws;
    size_t off = 0;
    auto alloc = [&](size_t bytes) { void* p = wsp + off; off = (off + bytes + 255) & ~(size_t)255; return p; };

    unsigned short* X    = (unsigned short*)alloc((size_t)MROWS * 360 * 2);
    unsigned short* XG   = (unsigned short*)alloc((size_t)MROWS * 520 * 2);
    unsigned short* FPC  = (unsigned short*)alloc((size_t)MROWS * 384 * 2);
    unsigned short* XQ   = (unsigned short*)alloc((size_t)MROWS * 264 * 2);
    unsigned short* T2b  = (unsigned short*)alloc((size_t)MROWS * 128 * 2);
    unsigned short* T3b  = (unsigned short*)alloc((size_t)MROWS * 128 * 2);
    unsigned short* QKSb = (unsigned short*)alloc((size_t)MROWS * 256 * 2);
    unsigned short* QWSb = (unsigned short*)alloc((size_t)MROWS * 40 * 2);
    unsigned short* OWNb = (unsigned short*)alloc((size_t)MROWS * 32 * 2);
    // composed bf16 weights
    unsigned short* FPW  = (unsigned short*)alloc(384 * 360 * 2);
    unsigned short* WGRU = (unsigned short*)alloc(1024 * 520 * 2);
    unsigned short* QWSW = (unsigned short*)alloc(40 * 264 * 2);
    unsigned short* WQKSO= (unsigned short*)alloc(256 * 32 * 2);
    unsigned short* rpW  = (unsigned short*)alloc(128 * 128 * 2);
    unsigned short* zbuf = (unsigned short*)alloc(256);
    // fp32 scratch
    float* WkAp = (float*)alloc(256 * 32 * 4);
    float* WvAp = (float*)alloc(256 * 32 * 4);
    float* WkEp = (float*)alloc(256 * 32 * 4);
    float* WvEp = (float*)alloc(256 * 32 * 4);
    float* Wkpp = (float*)alloc(256 * 32 * 4);
    float* WQKS_AE = (float*)alloc(256 * 256 * 4);
    float* WoVA = (float*)alloc(256 * 128 * 4);
    float* WoVE = (float*)alloc(256 * 128 * 4);
    float* bvAp = (float*)alloc(256 * 4);
    float* bvEp = (float*)alloc(256 * 4);
    float* bkpp = (float*)alloc(256 * 4);
    float* vall = (float*)alloc(768 * 4);
    float* qksb = (float*)alloc(256 * 4);
    float* fpb  = (float*)alloc(384 * 4);
    float* gbias= (float*)alloc(1024 * 4);
    float* rpb  = (float*)alloc(128 * 4);

    float* Qout = (float*)d_out;
    float* Hout = Qout + (size_t)MROWS * 22;

    auto tilesOf = [](const TOp& o) {
        return o.nb * (((o.I + 31) / 32) * ((o.J + 31) / 32));
    };

    // ---- prep ----
    cvt_misc<<<(MROWS * 64 + MROWS * 8 + 16 + 255) / 256, 256, 0, stream>>>(hidden, own_feats, XG, OWNb, zbuf);

    {   // mv1
        MOpSet S; S.n = 5; int waves = 0;
        S.ops[0] = {aA_Wv, 256, ally_b, nullptr, nullptr, bvAp, 256, 256};
        S.ops[1] = {aE_Wv, 256, en_b, nullptr, nullptr, bvEp, 256, 256};
        S.ops[2] = {kp_W, 256, en_b, nullptr, nullptr, bkpp, 256, 256};
        S.ops[3] = {nullptr, 0, nullptr, own_b, nullptr, vall, 256, 0};
        S.ops[4] = {role_W1, 128, pool_b2, role_b1, nullptr, rpb, 128, 128};
        for (int i = 0; i < S.n; i++) { S.waves[i] = S.ops[i].I; waves += S.ops[i].I; }
        mv_ops<<<(waves + 3) / 4, 256, 0, stream>>>(S);
    }
    {   // T1
        TOpSet S; S.n = 0; int grid = 0;
        auto add = [&](TOp o) { S.tiles[S.n] = tilesOf(o); grid += S.tiles[S.n]; S.ops[S.n++] = o; };
        add({1, aA_Wk, 256, 1, ally_W, 1, 32, WkAp, 32, 256, 32, 256, 1, 0, 0, 0});
        add({1, aA_Wv, 256, 1, ally_W, 1, 32, WvAp, 32, 256, 32, 256, 1, 0, 0, 0});
        add({1, aE_Wk, 256, 1, en_W, 1, 32, WkEp, 32, 256, 32, 256, 1, 0, 0, 0});
        add({1, aE_Wv, 256, 1, en_W, 1, 32, WvEp, 32, 256, 32, 256, 1, 0, 0, 0});
        add({1, kp_W, 256, 1, en_W, 1, 32, Wkpp, 32, 256, 32, 256, 1, 0, 0, 0});
        compose_tiled<<<grid, 256, 0, stream>>>(S);
    }
    {   // T2
        TOpSet S; S.n = 0; int grid = 0;
        auto add = [&](TOp o) { S.tiles[S.n] = tilesOf(o); grid += S.tiles[S.n]; S.ops[S.n++] = o; };
        add({1, WkAp, 1, 32, aA_Wq, 1, 256, WQKS_AE, 256, 32, 256, 64, 4, 2048, 16384, 8192});
        add({1, WkEp, 1, 32, aE_Wq, 1, 256, WQKS_AE + 128 * 256, 256, 32, 256, 64, 4, 2048, 16384, 8192});
        add({1, aA_Wo, 256, 1, WvAp, 1, 32, WoVA, 128, 256, 32, 64, 4, 64, 2048, 32});
        add({1, aE_Wo, 256, 1, WvEp, 1, 32, WoVE, 128, 256, 32, 64, 4, 64, 2048, 32});
        compose_tiled<<<grid, 256, 0, stream>>>(S);
    }
    {   // mv2
        MOpSet S; S.n = 3; int waves = 0;
        S.ops[0] = {aA_Wo, 256, bvAp, nullptr, nullptr, vall + 256, 256, 256};
        S.ops[1] = {aE_Wo, 256, bvEp, nullptr, nullptr, vall + 512, 256, 256};
        S.ops[2] = {WQKS_AE, 256, own_b, nullptr, nullptr, qksb, 256, 256};
        for (int i = 0; i < S.n; i++) { S.waves[i] = S.ops[i].I; waves += S.ops[i].I; }
        mv_ops<<<(waves + 3) / 4, 256, 0, stream>>>(S);
    }
    {   // mv3
        MOpSet S; S.n = 5; int waves = 0;
        S.ops[0] = {fuse_W1, 768, vall, fuse_b1, nullptr, fpb, 256, 768};
        S.ops[1] = {pool_W1, 768, vall, pool_b1, nullptr, fpb + 256, 128, 256};
        S.ops[2] = {gru_Wih, 264, fuse_b2, gru_bih, gru_bhh, gbias, 512, 256};
        S.ops[3] = {gru_Wih + 512 * 264, 264, fuse_b2, gru_bih + 512, nullptr, gbias + 512, 256, 256};
        S.ops[4] = {nullptr, 0, nullptr, gru_bhh + 512, nullptr, gbias + 768, 256, 0};
        for (int i = 0; i < S.n; i++) { S.waves[i] = S.ops[i].I; waves += S.ops[i].I; }
        mv_ops<<<(waves + 3) / 4, 256, 0, stream>>>(S);
    }
    {   // T3
        TOpSet S; S.n = 0; int grid = 0;
        auto add = [&](TOp o) { S.tiles[S.n] = tilesOf(o); grid += S.tiles[S.n]; S.ops[S.n++] = o; };
        // FPW rows 0..256 (fuse)
        add({0, fuse_W1, 768, 1, own_W, 1, 32, FPW, 360, 256, 32, 256, 1, 0, 0, 0});
        add({3, nullptr, 0, 0, nullptr, 0, 0, FPW + 32, 360, 256, 72, 0, 1, 0, 0, 0});
        add({0, fuse_W1 + 256, 768, 1, WoVA, 1, 128, FPW + 104, 360, 256, 128, 256, 1, 0, 0, 0});
        add({0, fuse_W1 + 512, 768, 1, WoVE, 1, 128, FPW + 232, 360, 256, 128, 256, 1, 0, 0, 0});
        // FPW rows 256..384 (pool)
        add({0, pool_W1, 768, 1, own_W, 1, 32, FPW + 256 * 360, 360, 128, 32, 256, 1, 0, 0, 0});
        add({0, pool_W1 + 256, 768, 1, ally_W, 1, 32, FPW + 256 * 360 + 32, 360, 128, 32, 256, 1, 0, 0, 0});
        add({0, pool_W1 + 512, 768, 1, en_W, 1, 32, FPW + 256 * 360 + 64, 360, 128, 32, 256, 1, 0, 0, 0});
        add({0, pool_W1 + 256, 768, 1, ally_b, 0, 1, FPW + 256 * 360 + 96, 360, 128, 1, 256, 1, 0, 0, 0});
        add({0, pool_W1 + 512, 768, 1, en_b, 0, 1, FPW + 256 * 360 + 97, 360, 128, 1, 256, 1, 0, 0, 0});
        add({3, nullptr, 0, 0, nullptr, 0, 0, FPW + 256 * 360 + 98, 360, 128, 262, 0, 1, 0, 0, 0});
        // WGRU rows 0..512 (r,z)
        add({0, gru_Wih, 264, 1, fuse_W2, 1, 256, WGRU, 520, 512, 256, 256, 1, 0, 0, 0});
        add({2, gru_Wih + 256, 264, 1, nullptr, 0, 0, WGRU + 256, 520, 512, 8, 0, 1, 0, 0, 0});
        add({2, gru_Whh, 256, 1, nullptr, 0, 0, WGRU + 264, 520, 512, 256, 0, 1, 0, 0, 0});
        // WGRU rows 512..768 (i_n)
        add({0, gru_Wih + 512 * 264, 264, 1, fuse_W2, 1, 256, WGRU + 512 * 520, 520, 256, 256, 256, 1, 0, 0, 0});
        add({2, gru_Wih + 512 * 264 + 256, 264, 1, nullptr, 0, 0, WGRU + 512 * 520 + 256, 520, 256, 8, 0, 1, 0, 0, 0});
        add({3, nullptr, 0, 0, nullptr, 0, 0, WGRU + 512 * 520 + 264, 520, 256, 256, 0, 1, 0, 0, 0});
        // WGRU rows 768..1024 (h_n)
        add({3, nullptr, 0, 0, nullptr, 0, 0, WGRU + 768 * 520, 520, 256, 264, 0, 1, 0, 0, 0});
        add({2, gru_Whh + 512 * 256, 256, 1, nullptr, 0, 0, WGRU + 768 * 520 + 264, 520, 256, 256, 0, 1, 0, 0, 0});
        // QWSW
        add({0, Wkpp, 1, 32, qp_W, 1, 264, QWSW, 264, 32, 264, 256, 1, 0, 0, 0});
        add({0, bkpp, 0, 1, qp_W, 1, 264, QWSW + 32 * 264, 264, 1, 264, 256, 1, 0, 0, 0});
        add({2, qn_W, 256, 1, nullptr, 0, 0, QWSW + 33 * 264, 264, 6, 256, 0, 1, 0, 0, 0});
        add({3, nullptr, 0, 0, nullptr, 0, 0, QWSW + 33 * 264 + 256, 264, 6, 8, 0, 1, 0, 0, 0});
        add({3, nullptr, 0, 0, nullptr, 0, 0, QWSW + 39 * 264, 264, 1, 264, 0, 1, 0, 0, 0});
        // WQKSO bf16
        add({0, WQKS_AE, 256, 1, own_W, 1, 32, WQKSO, 32, 256, 32, 256, 1, 0, 0, 0});
        // rpW = role_W1 @ pool_W2
        add({0, role_W1, 128, 1, pool_W2, 1, 128, rpW, 128, 128, 128, 128, 1, 0, 0, 0});
        compose_tiled<<<grid, 256, 0, stream>>>(S);
    }

    auto gemm = [&](const unsigned short* A, int lda, const unsigned short* Wm, const float* bias,
                    unsigned short* C, int ldc, int N, int K, int act) {
        gemm_bf16<64, 64><<<dim3(MROWS / 64, (N + 63) / 64), 256, 0, stream>>>(
            A, lda, Wm, bias, C, ldc, N, K, act, zbuf);
    };

    // ---- main chain ----
    gemm(OWNb, 32, WQKSO, qksb, QKSb, 256, 256, 32, 0);               // QKS
    glue_attn<<<MROWS / 4, 256, 0, stream>>>(ally_feats, enemy_feats, own_feats, QKSb, X);
    gemm(X, 360, FPW, fpb, FPC, 384, 384, 360, 1);                    // fuse1+pool1 (+gelu)
    ln_fp<<<MROWS / 4, 256, 0, stream>>>(FPC, fuse_g1, fuse_be1, pool_g1, pool_be1, XG, T2b);
    gemm(T2b, 128, rpW, rpb, T3b, 128, 128, 128, 1);                  // role1 (pool_W2 folded) + gelu
    ln_role<<<MROWS / 32, 256, 0, stream>>>(T3b, role_g1, role_be1, role_W2, role_b2, rln_g, rln_b, XG, XQ);
    gemm_gru<<<dim3(MROWS / 64, 4), 512, 0, stream>>>(XG, 520, WGRU, gbias, hidden,
                                                      Hout, XQ, 520, zbuf);   // fused GRU (8-wave)
    gemm(XQ, 264, QWSW, nullptr, QWSb, 40, 40, 264, 0);               // qws + c0 + q_normal
    glue_final<<<MROWS / 8, 256, 0, stream>>>(QWSb, enemy_feats, qn_b, Qout);
}